// Round 4
// baseline (234.662 us; speedup 1.0000x reference)
//
#include <hip/hip_runtime.h>
#include <cstdint>

// GRU RNN fused persistent kernel for MI355X (gfx950).  T=256,B=4096,D=128,H=16.
// Round 4: pure register pipeline — NO LDS, NO barriers, NO global_load_lds.
//
//  R1-R3 all capped at ~2.6-2.8 TB/s fetch regardless of pipeline depth or
//  barrier structure; common factor was global_load_lds staging. Hypothesis:
//  the LDS-DMA path has a shallow per-CU request queue that throttles pure-HBM
//  streaming (its wins in the guide are all L2-resident regimes). Plain
//  global->VGPR float4 loads are proven at 6.29 TB/s (m13).
//
//  - grid 256 (1 block/CU), 4 waves. Each wave owns 4 batch elems end-to-end:
//    loads its own A-fragments straight into registers, computes gx via MFMA
//    (D-fragment lands in exactly the lanes that scan it), register-only scan
//    (h = 1 float/thread, ds_bpermute broadcasts).
//  - A-fragment global addressing (per lane): row (t,e) = (li&3, wv*4+li>>2),
//    k-slice = ks*32 + lq*8 floats -> two f32x4 at +0/+16. Per instruction:
//    16 rows x 128B = full 64B lines, HBM-efficient.
//  - 2-chunk lookahead in two NAMED register sets (no runtime indexing ->
//    stays in VGPRs), compiler-counted vmcnt (loads fully unrolled), plus a
//    compile-time "memory" fence so prefetch issues can't sink below the scan.
//  - W_ih bf16 hi/lo split in registers; 3-pass MFMA (hh+lh+hl) ~f32-exact.

#define TT 256
#define BB 4096
#define DD 128
#define HH 16
#define TC 4
#define NCH (TT / TC)  // 64
#define EPB 16

typedef float    f32x4  __attribute__((ext_vector_type(4)));
typedef short    bf16x8 __attribute__((ext_vector_type(8)));
typedef uint32_t u32x4  __attribute__((ext_vector_type(4)));

__device__ __forceinline__ void split8(const f32x4& x0, const f32x4& x1,
                                       bf16x8& hi8, bf16x8& lo8) {
  float xs[8] = {x0.x, x0.y, x0.z, x0.w, x1.x, x1.y, x1.z, x1.w};
  uint32_t hiw[4], low[4];
#pragma unroll
  for (int j = 0; j < 4; ++j) {
    uint32_t e0 = __float_as_uint(xs[2 * j]);
    uint32_t e1 = __float_as_uint(xs[2 * j + 1]);
    uint32_t h0 = e0 & 0xFFFF0000u, h1 = e1 & 0xFFFF0000u;
    hiw[j] = (h0 >> 16) | h1;
    float l0 = xs[2 * j] - __uint_as_float(h0);
    float l1 = xs[2 * j + 1] - __uint_as_float(h1);
    low[j] = (__float_as_uint(l0) >> 16) | (__float_as_uint(l1) & 0xFFFF0000u);
  }
  hi8 = __builtin_bit_cast(bf16x8, (u32x4){hiw[0], hiw[1], hiw[2], hiw[3]});
  lo8 = __builtin_bit_cast(bf16x8, (u32x4){low[0], low[1], low[2], low[3]});
}

__global__ __launch_bounds__(256, 1) void gru_fused(
    const float* __restrict__ feat, const float* __restrict__ bmask,
    const float* __restrict__ hx0, const float* __restrict__ Wih,
    const float* __restrict__ Whh, const float* __restrict__ bih,
    const float* __restrict__ bhh, float* __restrict__ out) {
  const int tid  = threadIdx.x;
  const int lane = tid & 63;
  const int wv   = tid >> 6;   // wave 0..3 (independent pipeline)
  const int li   = lane & 15;  // MFMA row/col index == hidden unit si
  const int lq   = lane >> 4;  // MFMA quarter == elem-within-wave
  const int b0   = blockIdx.x * EPB;
  const int si   = li;
  const int se   = wv * 4 + lq;  // this thread's batch elem (0..15)

  // per-lane byte offset of this lane's A-row k-slice start within a chunk
  const int tqA = li & 3;              // timestep within chunk
  const int eA  = wv * 4 + (li >> 2);  // elem within block
  const size_t rowByte = (size_t)tqA * ((size_t)BB * DD * 4) +
                         (size_t)(b0 + eA) * (DD * 4) + (size_t)lq * 32;

  // ---- issue chunk-c loads into a named register set (A frags + masks) ----
  auto issue = [&](int c, f32x4 (&pa)[8], float (&pm)[4]) {
    const char* base =
        (const char*)feat + (size_t)c * ((size_t)TC * BB * DD * 4) + rowByte;
#pragma unroll
    for (int ks = 0; ks < 4; ++ks) {
      pa[2 * ks]     = *(const f32x4*)(base + ks * 128);
      pa[2 * ks + 1] = *(const f32x4*)(base + ks * 128 + 16);
    }
#pragma unroll
    for (int t2 = 0; t2 < 4; ++t2)
      pm[t2] = bmask[(size_t)(c * TC + t2) * BB + b0 + se];
  };

  f32x4 paA[8], paB[8];
  float pmA[4], pmB[4];
  issue(0, paA, pmA);  // start DMA before anything else
  issue(1, paB, pmB);
  asm volatile("" ::: "memory");

  // ---- W_ih fragments: global -> registers, bf16 hi/lo split ----
  bf16x8 Bh[4][3], Bl[4][3];
#pragma unroll
  for (int ks = 0; ks < 4; ++ks)
#pragma unroll
    for (int n = 0; n < 3; ++n) {
      const char* wp =
          (const char*)Wih + (16 * n + li) * 512 + ks * 128 + lq * 32;
      f32x4 w0 = *(const f32x4*)wp;
      f32x4 w1 = *(const f32x4*)(wp + 16);
      split8(w0, w1, Bh[ks][n], Bl[ks][n]);
    }

  // per-thread W_hh rows (gates r,z,n for unit si) + biases + h init
  float whhA[16], whhB[16], whhC[16];
#pragma unroll
  for (int j = 0; j < 16; ++j) {
    whhA[j] = Whh[si * HH + j];
    whhB[j] = Whh[(si + 16) * HH + j];
    whhC[j] = Whh[(si + 32) * HH + j];
  }
  const float bhA = bhh[si], bhB = bhh[si + 16], bhC = bhh[si + 32];
  const float biA = bih[si], biB = bih[si + 16], biC = bih[si + 32];
  float h = hx0[(size_t)(b0 + se) * HH + si];

  const int pbase = (lane & 48) << 2;  // 16-lane group base for bpermute

  // ---- one chunk: MFMA from reg set, reissue set for c+2, scan 4 steps ----
  auto body = [&](int c, f32x4 (&pa)[8], float (&pm)[4]) {
    float m0 = pm[0], m1 = pm[1], m2 = pm[2], m3 = pm[3];  // snapshot masks
    f32x4 acc0 = {0.f, 0.f, 0.f, 0.f};
    f32x4 acc1 = {0.f, 0.f, 0.f, 0.f};
    f32x4 acc2 = {0.f, 0.f, 0.f, 0.f};
#pragma unroll
    for (int ks = 0; ks < 4; ++ks) {
      bf16x8 Ah, Al;
      split8(pa[2 * ks], pa[2 * ks + 1], Ah, Al);
      acc0 = __builtin_amdgcn_mfma_f32_16x16x32_bf16(Ah, Bh[ks][0], acc0, 0, 0, 0);
      acc0 = __builtin_amdgcn_mfma_f32_16x16x32_bf16(Al, Bh[ks][0], acc0, 0, 0, 0);
      acc0 = __builtin_amdgcn_mfma_f32_16x16x32_bf16(Ah, Bl[ks][0], acc0, 0, 0, 0);
      acc1 = __builtin_amdgcn_mfma_f32_16x16x32_bf16(Ah, Bh[ks][1], acc1, 0, 0, 0);
      acc1 = __builtin_amdgcn_mfma_f32_16x16x32_bf16(Al, Bh[ks][1], acc1, 0, 0, 0);
      acc1 = __builtin_amdgcn_mfma_f32_16x16x32_bf16(Ah, Bl[ks][1], acc1, 0, 0, 0);
      acc2 = __builtin_amdgcn_mfma_f32_16x16x32_bf16(Ah, Bh[ks][2], acc2, 0, 0, 0);
      acc2 = __builtin_amdgcn_mfma_f32_16x16x32_bf16(Al, Bh[ks][2], acc2, 0, 0, 0);
      acc2 = __builtin_amdgcn_mfma_f32_16x16x32_bf16(Ah, Bl[ks][2], acc2, 0, 0, 0);
    }
    // refill this register set with chunk c+2 (2-deep lookahead)
    if (c + 2 < NCH) issue(c + 2, pa, pm);
    asm volatile("" ::: "memory");  // don't let prefetch sink below the scan

    // scan: 4 steps, registers + intra-wave bpermute, no barriers
    float mm[4] = {m0, m1, m2, m3};
#pragma unroll
    for (int tq = 0; tq < 4; ++tq) {
      float f = 1.0f - mm[tq];
      float d0 = 0.f, d1 = 0.f, d2 = 0.f;
#pragma unroll
      for (int j = 0; j < 16; ++j) {
        float hj = __uint_as_float((uint32_t)__builtin_amdgcn_ds_bpermute(
            pbase + 4 * j, (int)__float_as_uint(h)));
        d0 = __builtin_fmaf(whhA[j], hj, d0);
        d1 = __builtin_fmaf(whhB[j], hj, d1);
        d2 = __builtin_fmaf(whhC[j], hj, d2);
      }
      float g0 = acc0[tq] + biA;
      float g1 = acc1[tq] + biB;
      float g2 = acc2[tq] + biC;
      float r = 1.0f / (1.0f + __expf(-(g0 + f * d0 + bhA)));
      float z = 1.0f / (1.0f + __expf(-(g1 + f * d1 + bhB)));
      float a = g2 + r * (f * d2 + bhC);
      float n = 2.0f / (1.0f + __expf(-2.0f * a)) - 1.0f;  // tanh(a)
      float hm = f * h;
      h = n + z * (hm - n);  // (1-z)*n + z*h'
      out[((size_t)(c * TC + tq) * BB + b0 + se) * HH + si] = h;
    }
  };

  for (int cc = 0; cc < NCH; cc += 2) {
    body(cc, paA, pmA);
    body(cc + 1, paB, pmB);
  }
}

extern "C" void kernel_launch(void* const* d_in, const int* in_sizes, int n_in,
                              void* d_out, int out_size, void* d_ws,
                              size_t ws_size, hipStream_t stream) {
  const float* feat  = (const float*)d_in[0];
  const float* bmask = (const float*)d_in[1];
  const float* hx0   = (const float*)d_in[2];
  const float* Wih   = (const float*)d_in[3];
  const float* Whh   = (const float*)d_in[4];
  const float* bih   = (const float*)d_in[5];
  const float* bhh   = (const float*)d_in[6];
  float* out = (float*)d_out;
  gru_fused<<<dim3(BB / EPB), dim3(256), 0, stream>>>(feat, bmask, hx0, Wih,
                                                      Whh, bih, bhh, out);
}